// Round 6
// baseline (426.014 us; speedup 1.0000x reference)
//
#include <hip/hip_runtime.h>
#include <hip/hip_bf16.h>

// y[b,f,c] = sum_hw x[b,c,hw] * k[f,c,hw];  out[b, f*C + c]
// B=256, F=16, C=256, HW=1024, fp32.
//
// R4: launch_bounds(256,4) capped allocator at 64 VGPR -> loop spills; hint
// removed, kernel ~135us. R5/R6: RB=4 (64 named-float4 accs, ~120 VGPR
// demand) halves LDS traffic + x-load instrs per FMA; nontemporal x loads
// via native clang vector type (HIP_vector_type rejected by the builtin).

constexpr int Bb = 256;
constexpr int Ff = 16;
constexpr int Cc = 256;
constexpr int HW = 1024;
constexpr int CHW = Cc * HW;

constexpr int CH = 256;            // hw floats staged in LDS per chunk
constexpr int NCHUNK = HW / CH;    // 4
constexpr int BT = 64;             // b per block
constexpr int RB = 4;              // b per thread
constexpr int NTHREADS = (BT / RB) * 16;   // 256

typedef float vf4 __attribute__((ext_vector_type(4)));  // native vector for builtins

__device__ __forceinline__ float4 ntload4(const float* p) {
    vf4 v = __builtin_nontemporal_load((const vf4*)p);
    return make_float4(v.x, v.y, v.z, v.w);
}
__device__ __forceinline__ float dot4(float4 a, float4 b) {
    return a.x * b.x + a.y * b.y + a.z * b.z + a.w * b.w;
}
__device__ __forceinline__ float red16(float v) {
    v += __shfl_xor(v, 1);
    v += __shfl_xor(v, 2);
    v += __shfl_xor(v, 4);
    v += __shfl_xor(v, 8);
    return v;
}

__global__ __launch_bounds__(NTHREADS)   // no waves-per-eu hint (R4 lesson)
void sle_kernel(const float* __restrict__ x, const float* __restrict__ k,
                float* __restrict__ out) {
    __shared__ float ldsK[Ff * CH];           // 16 KiB

    const int t   = threadIdx.x;
    const int thw = t & 15;                   // hw split within 16-lane group
    const int tbg = t >> 4;                   // 0..15, b group
    const int btile = blockIdx.x & 3;         // 0..3 (same-c blocks adjacent)
    const int c     = blockIdx.x >> 2;        // 0..255
    const int b0    = btile * BT + tbg * RB;

    const float* x0 = x + (size_t)(b0 + 0) * CHW + (size_t)c * HW;
    const float* x1 = x + (size_t)(b0 + 1) * CHW + (size_t)c * HW;
    const float* x2 = x + (size_t)(b0 + 2) * CHW + (size_t)c * HW;
    const float* x3 = x + (size_t)(b0 + 3) * CHW + (size_t)c * HW;

    // acc[b][G]: 16 named float4 (component = f within group G of 4)
    float4 a00 = {0,0,0,0}, a01 = {0,0,0,0}, a02 = {0,0,0,0}, a03 = {0,0,0,0};
    float4 a10 = {0,0,0,0}, a11 = {0,0,0,0}, a12 = {0,0,0,0}, a13 = {0,0,0,0};
    float4 a20 = {0,0,0,0}, a21 = {0,0,0,0}, a22 = {0,0,0,0}, a23 = {0,0,0,0};
    float4 a30 = {0,0,0,0}, a31 = {0,0,0,0}, a32 = {0,0,0,0}, a33 = {0,0,0,0};

    for (int ch = 0; ch < NCHUNK; ++ch) {
        const int hw0 = ch * CH;
        __syncthreads();                      // prev chunk fully consumed
        {
            // stage K[f][hw0..hw0+CH): 4096 floats, 4 float4 per thread
            const int fr = t >> 4, lane16 = t & 15;
            const float4* src = (const float4*)(k + (size_t)fr * CHW
                                                  + (size_t)c * HW + hw0);
            float4* dst = (float4*)(ldsK + fr * CH);
#pragma unroll
            for (int q = 0; q < 4; ++q)
                dst[lane16 + 16 * q] = src[lane16 + 16 * q];
        }
        __syncthreads();

#pragma unroll
        for (int j = 0; j < 4; ++j) {
            const int f4  = thw + 16 * j;     // float4 index within chunk
            const int off = hw0 + 4 * f4;
            const float4 xv0 = ntload4(x0 + off);
            const float4 xv1 = ntload4(x1 + off);
            const float4 xv2 = ntload4(x2 + off);
            const float4 xv3 = ntload4(x3 + off);

#define ACC_G(G, A0, A1, A2, A3) {                                      \
            const float* kp = ldsK + (4 * (G)) * CH + 4 * f4;           \
            const float4 k0 = *(const float4*)(kp);                     \
            const float4 k1 = *(const float4*)(kp + CH);                \
            const float4 k2 = *(const float4*)(kp + 2 * CH);            \
            const float4 k3 = *(const float4*)(kp + 3 * CH);            \
            A0.x += dot4(xv0, k0); A0.y += dot4(xv0, k1);               \
            A0.z += dot4(xv0, k2); A0.w += dot4(xv0, k3);               \
            A1.x += dot4(xv1, k0); A1.y += dot4(xv1, k1);               \
            A1.z += dot4(xv1, k2); A1.w += dot4(xv1, k3);               \
            A2.x += dot4(xv2, k0); A2.y += dot4(xv2, k1);               \
            A2.z += dot4(xv2, k2); A2.w += dot4(xv2, k3);               \
            A3.x += dot4(xv3, k0); A3.y += dot4(xv3, k1);               \
            A3.z += dot4(xv3, k2); A3.w += dot4(xv3, k3); }

            ACC_G(0, a00, a10, a20, a30)
            ACC_G(1, a01, a11, a21, a31)
            ACC_G(2, a02, a12, a22, a32)
            ACC_G(3, a03, a13, a23, a33)
#undef ACC_G
        }
    }

    // reduce the 16 hw-split lanes; all lanes valid (butterfly)
#define RED4(A) { A.x = red16(A.x); A.y = red16(A.y); \
                  A.z = red16(A.z); A.w = red16(A.w); }
    RED4(a00) RED4(a01) RED4(a02) RED4(a03)
    RED4(a10) RED4(a11) RED4(a12) RED4(a13)
    RED4(a20) RED4(a21) RED4(a22) RED4(a23)
    RED4(a30) RED4(a31) RED4(a32) RED4(a33)
#undef RED4

    __syncthreads();                          // done reading ldsK as K-tile
    if (thw == 0) {
        float4* r0 = (float4*)(ldsK + (tbg * RB + 0) * Ff);
        float4* r1 = (float4*)(ldsK + (tbg * RB + 1) * Ff);
        float4* r2 = (float4*)(ldsK + (tbg * RB + 2) * Ff);
        float4* r3 = (float4*)(ldsK + (tbg * RB + 3) * Ff);
        r0[0] = a00; r0[1] = a01; r0[2] = a02; r0[3] = a03;
        r1[0] = a10; r1[1] = a11; r1[2] = a12; r1[3] = a13;
        r2[0] = a20; r2[1] = a21; r2[2] = a22; r2[3] = a23;
        r3[0] = a30; r3[1] = a31; r3[2] = a32; r3[3] = a33;
    }
    __syncthreads();

    // 1024 results (64 b x 16 f); 4 dword stores per thread
#pragma unroll
    for (int i = 0; i < (BT * Ff) / NTHREADS; ++i) {   // 4
        const int idx = t + NTHREADS * i;              // 0..1023
        const int bl  = idx >> 4;
        const int f   = idx & 15;
        out[(size_t)(btile * BT + bl) * (Ff * Cc) + f * Cc + c] = ldsK[idx];
    }
}

extern "C" void kernel_launch(void* const* d_in, const int* in_sizes, int n_in,
                              void* d_out, int out_size, void* d_ws, size_t ws_size,
                              hipStream_t stream) {
    const float* x = (const float*)d_in[0];
    const float* k = (const float*)d_in[1];
    float* out = (float*)d_out;
    const int grid = Cc * (Bb / BT);  // 1024
    sle_kernel<<<grid, NTHREADS, 0, stream>>>(x, k, out);
}

// Round 7
// 388.156 us; speedup vs baseline: 1.0975x; 1.0975x over previous
//
#include <hip/hip_runtime.h>
#include <hip/hip_bf16.h>

// y[b,f,c] = sum_hw x[b,c,hw] * k[f,c,hw];  out[b, f*C + c]
// B=256, F=16, C=256, HW=1024, fp32.
//
// R4 lesson: no waves-per-eu hint (caps allocator -> loop spills).
// R6 lesson: RB=4 + NT regressed; reverted to R4's RB=2 / grid 2048.
// R7: stage ALL of K[.,c,.] (64 KB LDS) once at kernel start; main loop is
// barrier-free so the x-stream (268 MB, sets the HBM floor) never stalls.

constexpr int Bb = 256;
constexpr int Ff = 16;
constexpr int Cc = 256;
constexpr int HW = 1024;
constexpr int CHW = Cc * HW;

constexpr int BT = 32;             // b per block
constexpr int RB = 2;              // b per thread
constexpr int NTHREADS = (BT / RB) * 16;   // 256
constexpr int NJ = HW / 4 / 16;    // 16 j-iters (whole hw range)

__device__ __forceinline__ float dot4(float4 a, float4 b) {
    return a.x * b.x + a.y * b.y + a.z * b.z + a.w * b.w;
}
__device__ __forceinline__ float red16(float v) {
    v += __shfl_xor(v, 1);
    v += __shfl_xor(v, 2);
    v += __shfl_xor(v, 4);
    v += __shfl_xor(v, 8);
    return v;
}

__global__ __launch_bounds__(NTHREADS)   // no waves-per-eu hint (R4 lesson)
void sle_kernel(const float* __restrict__ x, const float* __restrict__ k,
                float* __restrict__ out) {
    __shared__ float ldsK[Ff * HW];           // 64 KiB: whole K for this c

    const int t   = threadIdx.x;
    const int thw = t & 15;                   // hw split within 16-lane group
    const int tbg = t >> 4;                   // 0..15, b group
    const int btile = blockIdx.x & 7;         // 0..7 (same-c blocks adjacent)
    const int c     = blockIdx.x >> 3;        // 0..255
    const int b0    = btile * BT + tbg * RB;

    // ---- stage K[f][0..HW) for this c: 16384 floats, 16 float4/thread ----
    {
        const int fr = t >> 4, lane16 = t & 15;   // 16 threads per f-row
        const float4* src = (const float4*)(k + (size_t)fr * CHW + (size_t)c * HW);
        float4* dst = (float4*)(ldsK + fr * HW);
#pragma unroll
        for (int q = 0; q < 16; ++q)
            dst[lane16 + 16 * q] = src[lane16 + 16 * q];
    }
    __syncthreads();

    const float* x0 = x + (size_t)(b0 + 0) * CHW + (size_t)c * HW;
    const float* x1 = x + (size_t)(b0 + 1) * CHW + (size_t)c * HW;

    float4 a00 = {0,0,0,0}, a01 = {0,0,0,0}, a02 = {0,0,0,0}, a03 = {0,0,0,0};
    float4 a10 = {0,0,0,0}, a11 = {0,0,0,0}, a12 = {0,0,0,0}, a13 = {0,0,0,0};

    // ---- barrier-free main loop over the whole hw range ----
#pragma unroll 4
    for (int j = 0; j < NJ; ++j) {
        const int f4  = thw + 16 * j;         // float4 index in hw
        const int off = 4 * f4;
        const float4 xv0 = *(const float4*)(x0 + off);
        const float4 xv1 = *(const float4*)(x1 + off);

#define ACC_G(G, A0, A1) {                                              \
        const float* kp = ldsK + (4 * (G)) * HW + off;                  \
        const float4 k0 = *(const float4*)(kp);                         \
        const float4 k1 = *(const float4*)(kp + HW);                    \
        const float4 k2 = *(const float4*)(kp + 2 * HW);                \
        const float4 k3 = *(const float4*)(kp + 3 * HW);                \
        A0.x += dot4(xv0, k0); A0.y += dot4(xv0, k1);                   \
        A0.z += dot4(xv0, k2); A0.w += dot4(xv0, k3);                   \
        A1.x += dot4(xv1, k0); A1.y += dot4(xv1, k1);                   \
        A1.z += dot4(xv1, k2); A1.w += dot4(xv1, k3); }

        ACC_G(0, a00, a10)
        ACC_G(1, a01, a11)
        ACC_G(2, a02, a12)
        ACC_G(3, a03, a13)
#undef ACC_G
    }

    // reduce the 16 hw-split lanes; all lanes valid (butterfly)
#define RED4(A) { A.x = red16(A.x); A.y = red16(A.y); \
                  A.z = red16(A.z); A.w = red16(A.w); }
    RED4(a00) RED4(a01) RED4(a02) RED4(a03)
    RED4(a10) RED4(a11) RED4(a12) RED4(a13)
#undef RED4

    __syncthreads();                          // done reading ldsK as K-tile
    if (thw == 0) {
        float4* row0 = (float4*)(ldsK + (tbg * RB + 0) * Ff);
        float4* row1 = (float4*)(ldsK + (tbg * RB + 1) * Ff);
        row0[0] = a00; row0[1] = a01; row0[2] = a02; row0[3] = a03;
        row1[0] = a10; row1[1] = a11; row1[2] = a12; row1[3] = a13;
    }
    __syncthreads();

    // 512 results (32 b x 16 f); 2 dword stores per thread
#pragma unroll
    for (int i = 0; i < (BT * Ff) / NTHREADS; ++i) {   // 2
        const int idx = t + NTHREADS * i;              // 0..511
        const int bl  = idx >> 4;
        const int f   = idx & 15;
        out[(size_t)(btile * BT + bl) * (Ff * Cc) + f * Cc + c] = ldsK[idx];
    }
}

extern "C" void kernel_launch(void* const* d_in, const int* in_sizes, int n_in,
                              void* d_out, int out_size, void* d_ws, size_t ws_size,
                              hipStream_t stream) {
    const float* x = (const float*)d_in[0];
    const float* k = (const float*)d_in[1];
    float* out = (float*)d_out;
    const int grid = Cc * (Bb / BT);  // 2048
    sle_kernel<<<grid, NTHREADS, 0, stream>>>(x, k, out);
}